// Round 1
// baseline (20191.466 us; speedup 1.0000x reference)
//
#include <hip/hip_runtime.h>
#include <cstdint>
#include <cstddef>

#define BATCH 32
#define TLEN  512
#define DIN   1024
#define HDIM  1024
#define ZDIM  4096  // 4*H

// Block: 256 threads = 16 ksub-slices x 16 columns.
// Grid:  (64 col-blocks, 4 batch-groups) = 256 blocks (~1 per CU; LDS ~100 KB
//        forces 1 block/CU anyway).
// Each thread: 4 gates x 8 batches accumulators over a K-slice of 64 (x-part)
// + 64 (h-part); partials reduced across the 16 ksub slices in LDS.
__global__ __launch_bounds__(256, 1)
void lstm_step(const float* __restrict__ x,
               const float* __restrict__ W,      // [2048, 4096] row-major
               const float* __restrict__ bias,   // [4096]
               const float* __restrict__ hin,    // [32, 1024]
               float* __restrict__ hout,         // [32, 1024]
               float* __restrict__ cst,          // [32, 1024]
               float* __restrict__ out,          // [32, 512, 1024]
               int t)
{
    __shared__ float xs[8][DIN];        // 32 KB  x_t rows for this batch group
    __shared__ float hs[8][HDIM];       // 32 KB  h rows for this batch group
    __shared__ float red[256 * 33];     // ~33.8 KB  partial sums (pad 33 vs 32)
    __shared__ float zsh[32][16];       // 2 KB   reduced z: [gate*8+b][col]

    const int tid  = threadIdx.x;
    const int ksub = tid >> 4;          // 0..15
    const int cs   = tid & 15;          // 0..15
    const int cb   = blockIdx.x;        // 0..63
    const int bg   = blockIdx.y;        // 0..3
    const int col  = cb * 16 + cs;      // 0..1023 (gate-group column)

    // ---- stage x_t (reversed time) and h for our 8 batches ----
    const int tt = TLEN - 1 - t;
    for (int b = 0; b < 8; ++b) {
        const int bglob = bg * 8 + b;
        const float* xrow = x + ((size_t)bglob * TLEN + tt) * DIN;
        for (int k = tid; k < DIN; k += 256) xs[b][k] = xrow[k];
        const float* hrow = hin + (size_t)bglob * HDIM;
        for (int k = tid; k < HDIM; k += 256) hs[b][k] = hrow[k];
    }
    __syncthreads();

    // ---- partial dot products over our K slice ----
    float acc[4][8];
    #pragma unroll
    for (int g = 0; g < 4; ++g)
        #pragma unroll
        for (int b = 0; b < 8; ++b) acc[g][b] = 0.f;

    const int k0 = ksub * 64;

    // x-part: W rows [0, 1024)
    #pragma unroll 4
    for (int k = k0; k < k0 + 64; ++k) {
        const float* wr = W + (size_t)k * ZDIM + col;
        float w0 = wr[0];
        float w1 = wr[1024];
        float w2 = wr[2048];
        float w3 = wr[3072];
        #pragma unroll
        for (int b = 0; b < 8; ++b) {
            float xv = xs[b][k];
            acc[0][b] += xv * w0;
            acc[1][b] += xv * w1;
            acc[2][b] += xv * w2;
            acc[3][b] += xv * w3;
        }
    }
    // h-part: W rows [1024, 2048)
    #pragma unroll 4
    for (int k = k0; k < k0 + 64; ++k) {
        const float* wr = W + (size_t)(DIN + k) * ZDIM + col;
        float w0 = wr[0];
        float w1 = wr[1024];
        float w2 = wr[2048];
        float w3 = wr[3072];
        #pragma unroll
        for (int b = 0; b < 8; ++b) {
            float hv = hs[b][k];
            acc[0][b] += hv * w0;
            acc[1][b] += hv * w1;
            acc[2][b] += hv * w2;
            acc[3][b] += hv * w3;
        }
    }

    // ---- reduce the 16 ksub partials in LDS ----
    #pragma unroll
    for (int g = 0; g < 4; ++g)
        #pragma unroll
        for (int b = 0; b < 8; ++b)
            red[tid * 33 + (g * 8 + b)] = acc[g][b];
    __syncthreads();

    // 512 z values per block: (combo = gate*8+b) x (16 cols)
    for (int o = tid; o < 512; o += 256) {
        int c = o >> 4;          // combo 0..31
        int s = o & 15;          // colsub
        float sum = 0.f;
        #pragma unroll
        for (int ks = 0; ks < 16; ++ks)
            sum += red[(ks * 16 + s) * 33 + c];
        zsh[c][s] = sum;
    }
    __syncthreads();

    // ---- gate nonlinearity + state update: 8 batches x 16 cols = 128 cells ----
    if (tid < 128) {
        const int b = tid >> 4;
        const int s = tid & 15;
        const int bglob = bg * 8 + b;
        const int cg = cb * 16 + s;

        float zi = zsh[0 * 8 + b][s] + bias[cg];
        float zj = zsh[1 * 8 + b][s] + bias[1024 + cg];
        float zf = zsh[2 * 8 + b][s] + bias[2048 + cg];
        float zo = zsh[3 * 8 + b][s] + bias[3072 + cg];

        const size_t sidx = (size_t)bglob * HDIM + cg;
        float c_old = cst[sidx];

        float ig = 1.f / (1.f + expf(-zi));
        float fg = 1.f / (1.f + expf(-(zf + 1.0f)));   // forget bias = 1.0
        float og = 1.f / (1.f + expf(-zo));
        float jt = tanhf(zj);

        float c_new = fg * c_old + ig * jt;
        float h_new = og * tanhf(c_new);

        cst[sidx]  = c_new;
        hout[sidx] = h_new;
        out[((size_t)bglob * TLEN + t) * HDIM + cg] = c_new;
    }
}

extern "C" void kernel_launch(void* const* d_in, const int* in_sizes, int n_in,
                              void* d_out, int out_size, void* d_ws, size_t ws_size,
                              hipStream_t stream)
{
    const float* x    = (const float*)d_in[0];
    // d_in[1] = sl (int32, UNUSED by the reference)
    const float* W    = (const float*)d_in[2];
    const float* bias = (const float*)d_in[3];
    float* out = (float*)d_out;

    float* cst = (float*)d_ws;                 // [32,1024]
    float* ha  = cst + BATCH * HDIM;           // [32,1024]
    float* hb  = ha  + BATCH * HDIM;           // [32,1024]

    // zero c and both h buffers (ws is poisoned 0xAA before every call)
    hipMemsetAsync(d_ws, 0, (size_t)3 * BATCH * HDIM * sizeof(float), stream);

    dim3 grid(64, 4), block(256);
    for (int t = 0; t < TLEN; ++t) {
        const float* hin = (t & 1) ? hb : ha;
        float*       hout = (t & 1) ? ha : hb;
        lstm_step<<<grid, block, 0, stream>>>(x, W, bias, hin, hout, cst, out, t);
    }
}

// Round 2
// 12867.712 us; speedup vs baseline: 1.5692x; 1.5692x over previous
//
#include <hip/hip_runtime.h>
#include <cstdint>
#include <cstddef>

#define TLEN 512
#define HD   1024

typedef short bf16x8 __attribute__((ext_vector_type(8)));
typedef float f32x4  __attribute__((ext_vector_type(4)));

#define MFMA(a, b, c) __builtin_amdgcn_mfma_f32_16x16x32_bf16((a), (b), (c), 0, 0, 0)

static __device__ __forceinline__ unsigned short f2bf(float v) {
    unsigned u = __float_as_uint(v);
    u += 0x7fffu + ((u >> 16) & 1u);          // round-to-nearest-even
    return (unsigned short)(u >> 16);
}
static __device__ __forceinline__ float bf2f(unsigned short s) {
    return __uint_as_float((unsigned)s << 16);
}

// ws layout: bar (4096 B: leaf i at uint[i*32], root at uint[512], gen at uint[544])
//            then h buffers (shorts): hhi0[32K] hlo0[32K] hhi1[32K] hlo1[32K]
__global__ __launch_bounds__(256, 1)
void lstm_persist(const float* __restrict__ x,
                  const float* __restrict__ W,
                  const float* __restrict__ bias,
                  float* __restrict__ out,
                  unsigned* __restrict__ bar,
                  unsigned short* __restrict__ hbase)
{
    const int tid  = threadIdx.x;
    const int cb   = blockIdx.x;        // 0..255: owns h-cols [cb*4, cb*4+4)
    const int wv   = tid >> 6;          // wave 0..3: K-slice of 256 (x) + 256 (h)
    const int lane = tid & 63;
    const int mn   = lane & 15;         // A: m (batch row) / B: n (z-col)
    const int q    = lane >> 4;         // quad: k = q*8 + j

    __shared__ f32x4 red[4][2][64];     // [wave][Mtile][lane] partial acc
    __shared__ float zsh[32][17];       // reduced z[m][n], padded
    __shared__ float cls[32][4];        // persistent cell state (this block's cols)

    // ---- one-time: load persistent W fragments (hi/lo bf16 split) ----
    // z-col of lane-as-n: gate g = n>>2, hcol = cb*4 + (n&3)
    const int zc  = (mn >> 2) * 1024 + cb * 4 + (mn & 3);
    const int kx0 = wv * 256;           // x-weight rows base
    const int kh0 = 1024 + wv * 256;    // h-weight rows base

    bf16x8 wxh[8], wxl[8], whh[8], whl[8];
    #pragma unroll
    for (int kk = 0; kk < 8; ++kk) {
        #pragma unroll
        for (int j = 0; j < 8; ++j) {
            float v = W[(size_t)(kx0 + kk * 32 + q * 8 + j) * 4096 + zc];
            unsigned short h = f2bf(v);
            wxh[kk][j] = (short)h;
            wxl[kk][j] = (short)f2bf(v - bf2f(h));
            float v2 = W[(size_t)(kh0 + kk * 32 + q * 8 + j) * 4096 + zc];
            unsigned short h2 = f2bf(v2);
            whh[kk][j] = (short)h2;
            whl[kk][j] = (short)f2bf(v2 - bf2f(h2));
        }
    }

    // epilogue-thread constants + cell-state init
    float bi = 0.f, bj = 0.f, bff = 0.f, bo = 0.f;
    if (tid < 128) {
        int b = tid >> 2, hc = tid & 3;
        int c0 = cb * 4 + hc;
        bi  = bias[c0];
        bj  = bias[1024 + c0];
        bff = bias[2048 + c0];
        bo  = bias[3072 + c0];
        cls[b][hc] = 0.f;
    }
    __syncthreads();

    f32x4 acc0 = {0.f, 0.f, 0.f, 0.f};  // batches 0..15
    f32x4 acc1 = {0.f, 0.f, 0.f, 0.f};  // batches 16..31

    // x-part of step s (reads x[:, 511-s, :]), accumulated into acc
    auto do_xpart = [&](int tt) {
        const size_t b0 = ((size_t)mn * TLEN + tt) * HD + kx0 + q * 8;
        const size_t b1 = ((size_t)(mn + 16) * TLEN + tt) * HD + kx0 + q * 8;
        #pragma unroll
        for (int kk = 0; kk < 8; ++kk) {
            const float* p0 = x + b0 + kk * 32;
            const float* p1 = x + b1 + kk * 32;
            f32x4 a0 = *(const f32x4*)(p0);
            f32x4 a1 = *(const f32x4*)(p0 + 4);
            f32x4 c0 = *(const f32x4*)(p1);
            f32x4 c1 = *(const f32x4*)(p1 + 4);
            bf16x8 xh0, xl0, xh1, xl1;
            #pragma unroll
            for (int j = 0; j < 4; ++j) {
                float vv; unsigned short h;
                vv = a0[j]; h = f2bf(vv); xh0[j]     = (short)h; xl0[j]     = (short)f2bf(vv - bf2f(h));
                vv = a1[j]; h = f2bf(vv); xh0[4 + j] = (short)h; xl0[4 + j] = (short)f2bf(vv - bf2f(h));
                vv = c0[j]; h = f2bf(vv); xh1[j]     = (short)h; xl1[j]     = (short)f2bf(vv - bf2f(h));
                vv = c1[j]; h = f2bf(vv); xh1[4 + j] = (short)h; xl1[4 + j] = (short)f2bf(vv - bf2f(h));
            }
            acc0 = MFMA(xh0, wxh[kk], acc0);
            acc0 = MFMA(xl0, wxh[kk], acc0);
            acc0 = MFMA(xh0, wxl[kk], acc0);
            acc1 = MFMA(xh1, wxh[kk], acc1);
            acc1 = MFMA(xl1, wxh[kk], acc1);
            acc1 = MFMA(xh1, wxl[kk], acc1);
        }
    };

    auto do_hpart = [&](const unsigned short* Hh, const unsigned short* Hl) {
        const int off0 = mn * HD + (kh0 - 1024) + q * 8;
        const int off1 = off0 + 16 * HD;
        bf16x8 ah0[8], al0[8], ah1[8], al1[8];
        #pragma unroll
        for (int kk = 0; kk < 8; ++kk) {
            ah0[kk] = *(const bf16x8*)(Hh + off0 + kk * 32);
            al0[kk] = *(const bf16x8*)(Hl + off0 + kk * 32);
            ah1[kk] = *(const bf16x8*)(Hh + off1 + kk * 32);
            al1[kk] = *(const bf16x8*)(Hl + off1 + kk * 32);
        }
        #pragma unroll
        for (int kk = 0; kk < 8; ++kk) {
            acc0 = MFMA(ah0[kk], whh[kk], acc0);
            acc0 = MFMA(al0[kk], whh[kk], acc0);
            acc0 = MFMA(ah0[kk], whl[kk], acc0);
            acc1 = MFMA(ah1[kk], whh[kk], acc1);
            acc1 = MFMA(al1[kk], whh[kk], acc1);
            acc1 = MFMA(ah1[kk], whl[kk], acc1);
        }
    };

    unsigned short* hhi0 = hbase;
    unsigned short* hlo0 = hbase + 32768;
    unsigned short* hhi1 = hbase + 65536;
    unsigned short* hlo1 = hbase + 98304;

    do_xpart(TLEN - 1);   // prefold x-part of step 0

    for (int t = 0; t < TLEN; ++t) {
        const unsigned short* Hh = (t & 1) ? hhi1 : hhi0;
        const unsigned short* Hl = (t & 1) ? hlo1 : hlo0;
        unsigned short* Ph = (t & 1) ? hhi0 : hhi1;   // publish buffer
        unsigned short* Pl = (t & 1) ? hlo0 : hlo1;

        do_hpart(Hh, Hl);   // acc now holds full z(t) partials (x-part was prefolded)

        red[wv][0][lane] = acc0;
        red[wv][1][lane] = acc1;
        __syncthreads();
        if (tid < 128) {
            int tile = tid >> 6, l = tid & 63;
            f32x4 s = red[0][tile][l];
            s += red[1][tile][l];
            s += red[2][tile][l];
            s += red[3][tile][l];
            int nn = l & 15, qq = l >> 4;
            int m0 = tile * 16 + qq * 4;
            zsh[m0 + 0][nn] = s[0];
            zsh[m0 + 1][nn] = s[1];
            zsh[m0 + 2][nn] = s[2];
            zsh[m0 + 3][nn] = s[3];
        }
        __syncthreads();
        if (tid < 128) {
            int b = tid >> 2, hc = tid & 3;
            float zi = zsh[b][hc]      + bi;
            float zj = zsh[b][4 + hc]  + bj;
            float zf = zsh[b][8 + hc]  + bff;
            float zo = zsh[b][12 + hc] + bo;
            float co = cls[b][hc];
            float ig = 1.f / (1.f + expf(-zi));
            float fg = 1.f / (1.f + expf(-(zf + 1.0f)));   // forget bias
            float og = 1.f / (1.f + expf(-zo));
            float jt = tanhf(zj);
            float cn = fg * co + ig * jt;
            float hn = og * tanhf(cn);
            cls[b][hc] = cn;
            __builtin_nontemporal_store(cn, &out[((size_t)b * TLEN + t) * HD + cb * 4 + hc]);
            unsigned short hh = f2bf(hn);
            unsigned short hl = f2bf(hn - bf2f(hh));
            int wi = b * HD + cb * 4 + hc;
            Ph[wi] = hh;
            Pl[wi] = hl;
        }
        acc0 = (f32x4){0.f, 0.f, 0.f, 0.f};
        acc1 = (f32x4){0.f, 0.f, 0.f, 0.f};
        __syncthreads();   // drains every wave's h stores (vmcnt) before arrival

        if (t + 1 < TLEN) {
            const unsigned target = (unsigned)t * 16u + 15u;
            if (tid == 0) {
                __builtin_amdgcn_fence(__ATOMIC_RELEASE, "agent");   // flush this XCD's L2
                unsigned old = __hip_atomic_fetch_add(&bar[(cb >> 4) * 32], 1u,
                                   __ATOMIC_RELAXED, __HIP_MEMORY_SCOPE_AGENT);
                if (old == target) {
                    unsigned r = __hip_atomic_fetch_add(&bar[512], 1u,
                                   __ATOMIC_RELAXED, __HIP_MEMORY_SCOPE_AGENT);
                    if (r == target) {
                        __hip_atomic_store(&bar[544], (unsigned)(t + 1),
                                   __ATOMIC_RELEASE, __HIP_MEMORY_SCOPE_AGENT);
                    }
                }
            }
            // overlap barrier wait with next step's x-part (no h dependency)
            do_xpart(TLEN - 2 - t);
            if (tid == 0) {
                while (__hip_atomic_load(&bar[544], __ATOMIC_RELAXED,
                           __HIP_MEMORY_SCOPE_AGENT) < (unsigned)(t + 1)) {
                    __builtin_amdgcn_s_sleep(1);
                }
            }
            __syncthreads();
            __builtin_amdgcn_fence(__ATOMIC_ACQUIRE, "agent");   // invalidate stale h lines
        }
    }
}

extern "C" void kernel_launch(void* const* d_in, const int* in_sizes, int n_in,
                              void* d_out, int out_size, void* d_ws, size_t ws_size,
                              hipStream_t stream)
{
    (void)in_sizes; (void)n_in; (void)out_size; (void)ws_size;
    const float* x    = (const float*)d_in[0];
    // d_in[1] = sl (unused by reference)
    const float* W    = (const float*)d_in[2];
    const float* bias = (const float*)d_in[3];
    float* out = (float*)d_out;

    unsigned* bar = (unsigned*)d_ws;
    unsigned short* hbase = (unsigned short*)((char*)d_ws + 4096);

    // zero barrier state + both h double-buffers (hi/lo): 4096 + 4*65536 B
    hipMemsetAsync(d_ws, 0, 4096 + 262144, stream);

    lstm_persist<<<256, 256, 0, stream>>>(x, W, bias, out, bar, hbase);
}

// Round 3
// 7533.931 us; speedup vs baseline: 2.6801x; 1.7080x over previous
//
#include <hip/hip_runtime.h>
#include <cstdint>
#include <cstddef>

#define TLEN 512
#define HD   1024

typedef short bf16x8 __attribute__((ext_vector_type(8)));
typedef float f32x4  __attribute__((ext_vector_type(4)));

#define MFMA(a, b, c) __builtin_amdgcn_mfma_f32_16x16x32_bf16((a), (b), (c), 0, 0, 0)

static __device__ __forceinline__ unsigned short f2bf(float v) {
    unsigned u = __float_as_uint(v);
    u += 0x7fffu + ((u >> 16) & 1u);          // round-to-nearest-even
    return (unsigned short)(u >> 16);
}
static __device__ __forceinline__ float bf2f(unsigned short s) {
    return __uint_as_float((unsigned)s << 16);
}

// Coherent (L2-bypassing) 16B h-load as two agent-scope relaxed 8B atomic
// loads — compiler emits proper cache bits AND tracks vmcnt for us.
static __device__ __forceinline__ bf16x8 ld_h16(const unsigned short* p) {
    union { unsigned long long u[2]; bf16x8 v; } r;
    r.u[0] = __hip_atomic_load((const unsigned long long*)p,
                               __ATOMIC_RELAXED, __HIP_MEMORY_SCOPE_AGENT);
    r.u[1] = __hip_atomic_load((const unsigned long long*)p + 1,
                               __ATOMIC_RELAXED, __HIP_MEMORY_SCOPE_AGENT);
    return r.v;
}

// Write-through store (past L2, to coherent L3). Drained by explicit vmcnt(0).
static __device__ __forceinline__ void st_bypass_u16(unsigned short* p, unsigned short v) {
    unsigned vv = v;
    asm volatile("global_store_short %0, %1, off sc0 sc1" :: "v"(p), "v"(vv) : "memory");
}

// ws: bar (4096 B: leaf i at uint[i*32], root uint[512], gen uint[544]),
//     then h buffers (ushort): hhi0[32K] hlo0[32K] hhi1[32K] hlo1[32K]
__global__ __launch_bounds__(512, 2)
void lstm_persist(const float* __restrict__ x,
                  const float* __restrict__ W,
                  const float* __restrict__ bias,
                  float* __restrict__ out,
                  unsigned* __restrict__ bar,
                  unsigned short* __restrict__ hbase)
{
    const int tid  = threadIdx.x;
    const int cb   = blockIdx.x;        // owns h-cols [cb*4, cb*4+4)
    const int wv   = tid >> 6;          // wave 0..7: K-slice of 128 (x) + 128 (h)
    const int lane = tid & 63;
    const int mn   = lane & 15;         // A: m (batch) / B: n (z-col)
    const int q    = lane >> 4;         // k = q*8 + j within a K-32 tile

    __shared__ f32x4 red[8][2][64];     // 16 KB partials
    __shared__ float zsh[32][17];
    __shared__ float cls[32][4];        // persistent cell state

    // ---- one-time: persistent W fragments (hi/lo bf16 split), register-resident ----
    const int zc  = (mn >> 2) * 1024 + cb * 4 + (mn & 3);
    const int kx0 = wv * 128;

    bf16x8 wxh[4], wxl[4], whh[4], whl[4];
    #pragma unroll
    for (int kk = 0; kk < 4; ++kk) {
        #pragma unroll
        for (int j = 0; j < 8; ++j) {
            const int r = kx0 + kk * 32 + q * 8 + j;
            float v = W[(size_t)r * 4096 + zc];
            unsigned short h = f2bf(v);
            wxh[kk][j] = (short)h;
            wxl[kk][j] = (short)f2bf(v - bf2f(h));
            float v2 = W[(size_t)(1024 + r) * 4096 + zc];
            unsigned short h2 = f2bf(v2);
            whh[kk][j] = (short)h2;
            whl[kk][j] = (short)f2bf(v2 - bf2f(h2));
        }
    }

    float bi = 0.f, bj = 0.f, bff = 0.f, bo = 0.f;
    if (tid < 128) {
        int b = tid >> 2, hc = tid & 3;
        int c0 = cb * 4 + hc;
        bi  = bias[c0];
        bj  = bias[1024 + c0];
        bff = bias[2048 + c0];
        bo  = bias[3072 + c0];
        cls[b][hc] = 0.f;
    }
    __syncthreads();

    f32x4 acc0 = {0.f, 0.f, 0.f, 0.f};
    f32x4 acc1 = {0.f, 0.f, 0.f, 0.f};

    auto do_xpart = [&](int tt) {
        const size_t b0 = ((size_t)mn * TLEN + tt) * HD + kx0 + q * 8;
        const size_t b1 = ((size_t)(mn + 16) * TLEN + tt) * HD + kx0 + q * 8;
        #pragma unroll
        for (int kk = 0; kk < 4; ++kk) {
            const float* p0 = x + b0 + kk * 32;
            const float* p1 = x + b1 + kk * 32;
            f32x4 a0 = *(const f32x4*)(p0);
            f32x4 a1 = *(const f32x4*)(p0 + 4);
            f32x4 c0 = *(const f32x4*)(p1);
            f32x4 c1 = *(const f32x4*)(p1 + 4);
            bf16x8 xh0, xl0, xh1, xl1;
            #pragma unroll
            for (int j = 0; j < 4; ++j) {
                float vv; unsigned short h;
                vv = a0[j]; h = f2bf(vv); xh0[j]     = (short)h; xl0[j]     = (short)f2bf(vv - bf2f(h));
                vv = a1[j]; h = f2bf(vv); xh0[4 + j] = (short)h; xl0[4 + j] = (short)f2bf(vv - bf2f(h));
                vv = c0[j]; h = f2bf(vv); xh1[j]     = (short)h; xl1[j]     = (short)f2bf(vv - bf2f(h));
                vv = c1[j]; h = f2bf(vv); xh1[4 + j] = (short)h; xl1[4 + j] = (short)f2bf(vv - bf2f(h));
            }
            acc0 = MFMA(xh0, wxh[kk], acc0);
            acc0 = MFMA(xl0, wxh[kk], acc0);
            acc0 = MFMA(xh0, wxl[kk], acc0);
            acc1 = MFMA(xh1, wxh[kk], acc1);
            acc1 = MFMA(xl1, wxh[kk], acc1);
            acc1 = MFMA(xh1, wxl[kk], acc1);
        }
    };

    auto do_hpart = [&](const unsigned short* Hh, const unsigned short* Hl) {
        const int off0 = mn * HD + kx0 + q * 8;
        const int off1 = off0 + 16 * HD;
        bf16x8 ah0[4], al0[4], ah1[4], al1[4];
        #pragma unroll
        for (int kk = 0; kk < 4; ++kk) {
            ah0[kk] = ld_h16(Hh + off0 + kk * 32);
            al0[kk] = ld_h16(Hl + off0 + kk * 32);
            ah1[kk] = ld_h16(Hh + off1 + kk * 32);
            al1[kk] = ld_h16(Hl + off1 + kk * 32);
        }
        #pragma unroll
        for (int kk = 0; kk < 4; ++kk) {
            acc0 = MFMA(ah0[kk], whh[kk], acc0);
            acc0 = MFMA(al0[kk], whh[kk], acc0);
            acc0 = MFMA(ah0[kk], whl[kk], acc0);
            acc1 = MFMA(ah1[kk], whh[kk], acc1);
            acc1 = MFMA(al1[kk], whh[kk], acc1);
            acc1 = MFMA(ah1[kk], whl[kk], acc1);
        }
    };

    unsigned short* hhi0 = hbase;
    unsigned short* hlo0 = hbase + 32768;
    unsigned short* hhi1 = hbase + 65536;
    unsigned short* hlo1 = hbase + 98304;

    do_xpart(TLEN - 1);   // prefold x-part of step 0

    for (int t = 0; t < TLEN; ++t) {
        const unsigned short* Hh = (t & 1) ? hhi1 : hhi0;
        const unsigned short* Hl = (t & 1) ? hlo1 : hlo0;
        unsigned short* Ph = (t & 1) ? hhi0 : hhi1;
        unsigned short* Pl = (t & 1) ? hlo0 : hlo1;

        do_hpart(Hh, Hl);

        red[wv][0][lane] = acc0;
        red[wv][1][lane] = acc1;
        __syncthreads();
        if (tid < 128) {
            int tile = tid >> 6, l = tid & 63;
            f32x4 s = red[0][tile][l];
            #pragma unroll
            for (int w = 1; w < 8; ++w) s += red[w][tile][l];
            int nn = l & 15, qq = l >> 4;
            int m0 = tile * 16 + qq * 4;
            zsh[m0 + 0][nn] = s[0];
            zsh[m0 + 1][nn] = s[1];
            zsh[m0 + 2][nn] = s[2];
            zsh[m0 + 3][nn] = s[3];
        }
        __syncthreads();
        if (tid < 128) {
            int b = tid >> 2, hc = tid & 3;
            float zi = zsh[b][hc]      + bi;
            float zj = zsh[b][4 + hc]  + bj;
            float zf = zsh[b][8 + hc]  + bff;
            float zo = zsh[b][12 + hc] + bo;
            float co = cls[b][hc];
            float ig = 1.f / (1.f + expf(-zi));
            float fg = 1.f / (1.f + expf(-(zf + 1.0f)));   // forget bias = 1.0
            float og = 1.f / (1.f + expf(-zo));
            float jt = tanhf(zj);
            float cn = fg * co + ig * jt;
            float hn = og * tanhf(cn);
            cls[b][hc] = cn;
            __builtin_nontemporal_store(cn, &out[((size_t)b * TLEN + t) * HD + cb * 4 + hc]);
            unsigned short hh = f2bf(hn);
            unsigned short hl = f2bf(hn - bf2f(hh));
            int wi = b * HD + cb * 4 + hc;
            st_bypass_u16(Ph + wi, hh);
            st_bypass_u16(Pl + wi, hl);
        }
        acc0 = (f32x4){0.f, 0.f, 0.f, 0.f};
        acc1 = (f32x4){0.f, 0.f, 0.f, 0.f};
        // drain THIS wave's publish stores to L3 before barrier arrival
        asm volatile("s_waitcnt vmcnt(0)" ::: "memory");
        __syncthreads();

        if (t + 1 < TLEN) {
            const unsigned target = (unsigned)t * 16u + 15u;
            if (tid == 0) {
                unsigned old = __hip_atomic_fetch_add(&bar[(cb >> 4) * 32], 1u,
                                   __ATOMIC_RELAXED, __HIP_MEMORY_SCOPE_AGENT);
                if (old == target) {
                    unsigned r = __hip_atomic_fetch_add(&bar[512], 1u,
                                   __ATOMIC_RELAXED, __HIP_MEMORY_SCOPE_AGENT);
                    if (r == target) {
                        __hip_atomic_store(&bar[544], (unsigned)(t + 1),
                                   __ATOMIC_RELAXED, __HIP_MEMORY_SCOPE_AGENT);
                    }
                }
            }
            // overlap the barrier wait with next step's x-part (h-independent)
            do_xpart(TLEN - 2 - t);
            if (tid == 0) {
                while (__hip_atomic_load(&bar[544], __ATOMIC_RELAXED,
                           __HIP_MEMORY_SCOPE_AGENT) < (unsigned)(t + 1)) {
                    __builtin_amdgcn_s_sleep(1);
                }
            }
            __syncthreads();
            // NO acquire fence: h reads bypass L2 (coherent at L3);
            // x/W/bias are read-only; out is write-only; c lives in LDS.
        }
    }
}

extern "C" void kernel_launch(void* const* d_in, const int* in_sizes, int n_in,
                              void* d_out, int out_size, void* d_ws, size_t ws_size,
                              hipStream_t stream)
{
    (void)in_sizes; (void)n_in; (void)out_size; (void)ws_size;
    const float* x    = (const float*)d_in[0];
    // d_in[1] = sl (unused by reference)
    const float* W    = (const float*)d_in[2];
    const float* bias = (const float*)d_in[3];
    float* out = (float*)d_out;

    unsigned* bar = (unsigned*)d_ws;
    unsigned short* hbase = (unsigned short*)((char*)d_ws + 4096);

    // zero barrier state + h double-buffers; stream-ordered memset is
    // cache-coherent w.r.t. the following kernel (kernel-boundary flush)
    hipMemsetAsync(d_ws, 0, 4096 + 262144, stream);

    lstm_persist<<<256, 512, 0, stream>>>(x, W, bias, out, bar, hbase);
}